// Round 13
// baseline (488.343 us; speedup 1.0000x reference)
//
#include <hip/hip_runtime.h>
#include <hip/hip_bf16.h>
#include <stdint.h>

// BaseLayer MoE block. I/O f32, GEMMs bf16 MFMA. T=8192, D=1024, F=4096, E=8.
// R13: R11 structure (block-wide assign with __syncthreads; BK=32 ring GEMMs)
// + atomic de-serialization in assign: wave-aggregated histogram adds
// (ballot/ffs/shfl distinct-bucket loop) and wave_claim (1 atomic per wave)
// for all position counters. R12's barrier-free wave-sync refine (compiler
// LDS-caching fault) is abandoned.

#define T_TOK 8192
#define DM    1024
#define FF    4096
#define NE    8
#define CAP   1024

typedef __attribute__((ext_vector_type(8))) __bf16 bf16x8;
typedef __attribute__((ext_vector_type(4))) float  f32x4;

__device__ __forceinline__ unsigned short f2bf(float f) {
  unsigned u = __float_as_uint(f);
  u += 0x7FFFu + ((u >> 16) & 1u);   // round-to-nearest-even
  return (unsigned short)(u >> 16);
}
__device__ __forceinline__ void gload_lds16(const void* g, void* l) {
  __builtin_amdgcn_global_load_lds(
      (const __attribute__((address_space(1))) unsigned int*)(uintptr_t)g,
      (__attribute__((address_space(3))) unsigned int*)l, 16, 0, 0);
}

// ---------------- LN + centroid scores (scores stored [E][T]) ---------------
__global__ __launch_bounds__(256) void ln_scores_k(
    const float* __restrict__ x, const float* __restrict__ g,
    const float* __restrict__ b, const float* __restrict__ cent,
    unsigned short* __restrict__ nrm, float* __restrict__ scores) {
  const int t = blockIdx.x, tid = threadIdx.x;
  const int lane = tid & 63, w = tid >> 6;
  float4 v = ((const float4*)(x + (size_t)t * DM))[tid];
  float f0 = v.x, f1 = v.y, f2 = v.z, f3 = v.w;
  float s = f0 + f1 + f2 + f3;
  float sq = f0 * f0 + f1 * f1 + f2 * f2 + f3 * f3;
#pragma unroll
  for (int o = 32; o > 0; o >>= 1) { s += __shfl_xor(s, o); sq += __shfl_xor(sq, o); }
  __shared__ float red[8];
  if (lane == 0) { red[w] = s; red[4 + w] = sq; }
  __syncthreads();
  float S = red[0] + red[1] + red[2] + red[3];
  float SQ = red[4] + red[5] + red[6] + red[7];
  float mu = S * (1.0f / DM);
  float var = SQ * (1.0f / DM) - mu * mu;
  float rstd = rsqrtf(var + 1e-5f);
  float4 gv = ((const float4*)g)[tid];
  float4 bv = ((const float4*)b)[tid];
  float n0 = (f0 - mu) * rstd * gv.x + bv.x;
  float n1 = (f1 - mu) * rstd * gv.y + bv.y;
  float n2 = (f2 - mu) * rstd * gv.z + bv.z;
  float n3 = (f3 - mu) * rstd * gv.w + bv.w;
  ushort4 o4;
  o4.x = f2bf(n0); o4.y = f2bf(n1); o4.z = f2bf(n2); o4.w = f2bf(n3);
  ((ushort4*)(nrm + (size_t)t * DM))[tid] = o4;
  __shared__ float sred[4];
  for (int e = 0; e < NE; ++e) {
    float4 cv = ((const float4*)(cent + e * DM))[tid];
    float p = n0 * cv.x + n1 * cv.y + n2 * cv.z + n3 * cv.w;
#pragma unroll
    for (int o = 32; o > 0; o >>= 1) p += __shfl_xor(p, o);
    if (lane == 0) sred[w] = p;
    __syncthreads();
    if (tid == 0) scores[(size_t)e * T_TOK + t] = sred[0] + sred[1] + sred[2] + sred[3];
    __syncthreads();
  }
}

// ---- wave helpers ----------------------------------------------------------
// Aggregated counter claim: 1 atomic per wave; valid under divergence (if any
// lane of the wave is active, lane index 0 of the ACTIVE set may not be 0 --
// so use the first active lane as leader).
__device__ __forceinline__ unsigned wave_claim(bool pred, unsigned* ctr, int lane) {
  unsigned long long b = __ballot(pred);
  unsigned cnt = (unsigned)__popcll(b);
  unsigned long long act = __ballot(true);
  int leader = __ffsll((unsigned long long)act) - 1;
  unsigned base = 0;
  if (lane == leader && cnt) base = atomicAdd(ctr, cnt);
  base = __shfl(base, leader);
  return base + (unsigned)__popcll(b & ((1ull << lane) - 1ull));
}
// Wave-aggregated histogram add: one atomic per DISTINCT bucket in the wave.
__device__ __forceinline__ void wave_hist_add(unsigned bucket, unsigned* hist,
                                              int lane) {
  bool done = false;
  while (true) {
    unsigned long long rem = __ballot(!done);
    if (!rem) break;
    int src = __ffsll((unsigned long long)rem) - 1;
    unsigned b0 = __shfl(bucket, src);
    bool match = (!done && bucket == b0);
    unsigned long long mb = __ballot(match);
    if (lane == src) atomicAdd(&hist[b0], (unsigned)__popcll(mb));
    if (match) done = true;
  }
}
// Suffix-scan hist[256] (4 buckets/lane): find pivot bucket; S[0]=need io.
__device__ __forceinline__ void pivot_scan(const unsigned* hist, unsigned* S,
                                           int l) {
  unsigned v0 = hist[4 * l], v1 = hist[4 * l + 1];
  unsigned v2 = hist[4 * l + 2], v3 = hist[4 * l + 3];
  unsigned own = v0 + v1 + v2 + v3;
  unsigned s = own;
#pragma unroll
  for (int off = 1; off < 64; off <<= 1) {
    unsigned t = __shfl_down(s, off);
    if (l + off < 64) s += t;
  }
  unsigned i3 = (s - own) + v3;
  unsigned i2 = i3 + v2;
  unsigned i1 = i2 + v1;
  unsigned i0 = i1 + v0;
  unsigned need = S[0];
  if (i0 >= need && i0 - v0 < need) { S[1] = 4 * l + 0; S[0] = need - (i0 - v0); }
  if (i1 >= need && i1 - v1 < need) { S[1] = 4 * l + 1; S[0] = need - (i1 - v1); }
  if (i2 >= need && i2 - v2 < need) { S[1] = 4 * l + 2; S[0] = need - (i2 - v2); }
  if (i3 >= need && i3 - v3 < need) { S[1] = 4 * l + 3; S[0] = need - (i3 - v3); }
}
// Select S[0] lowest-index set bits of bmap (8192 bits); emit via S[2].
__device__ __forceinline__ void tie_select(const unsigned* bmap, unsigned* S,
                                           int* tokdst, unsigned char* taken,
                                           int l) {
  unsigned wds[4] = {bmap[4 * l], bmap[4 * l + 1], bmap[4 * l + 2], bmap[4 * l + 3]};
  unsigned cnt = __popc(wds[0]) + __popc(wds[1]) + __popc(wds[2]) + __popc(wds[3]);
  unsigned p = cnt;
#pragma unroll
  for (int off = 1; off < 64; off <<= 1) {
    unsigned t = __shfl_up(p, off);
    if (l >= off) p += t;
  }
  unsigned base = p - cnt;
  const unsigned r = S[0];
#pragma unroll
  for (int c = 0; c < 4; ++c) {
    unsigned word = wds[c];
    while (word && base < r) {
      int b = __ffs(word) - 1; word &= word - 1;
      int i = (4 * l + c) * 32 + b;
      unsigned pp = atomicAdd(&S[2], 1u);
      tokdst[pp] = i; taken[i] = 1;
      ++base;
    }
    base += __popc(word);
  }
}

// ---- assignment body: R11 block-wide structure + aggregated atomics --------
__device__ void assign_body(const float* __restrict__ scores,
                            int* __restrict__ tok, char* smem) {
  unsigned*       key   = (unsigned*)smem;                   // 32 KB
  unsigned short* candA = (unsigned short*)(smem + 32768);   // 16 KB
  unsigned short* candB = (unsigned short*)(smem + 49152);   // 16 KB
  unsigned char*  taken = (unsigned char*)(smem + 65536);    //  8 KB
  unsigned*       hist  = (unsigned*)(smem + 73728);         //  1 KB
  unsigned*       bmap  = (unsigned*)(smem + 74752);         //  1 KB
  unsigned*       S     = (unsigned*)(smem + 75776);         // scalars
  const int tid = threadIdx.x, lane = tid & 63;
  for (int i = tid; i < T_TOK; i += 1024) taken[i] = 0;
  __syncthreads();
  for (int e = 0; e < NE; ++e) {
    const float* se = scores + (size_t)e * T_TOK;
    if (tid < 256) hist[tid] = 0;
    if (tid == 0) { S[0] = CAP; S[2] = 0; S[4] = 0; }
    __syncthreads();
    // S1: keys + aggregated level-0 histogram (top byte clusters on exponent)
#pragma unroll
    for (int j = 0; j < 8; ++j) {
      int i = j * 1024 + tid;
      unsigned k = 0;
      if (!taken[i]) {
        unsigned bb = __float_as_uint(se[i]);
        k = (bb & 0x80000000u) ? ~bb : (bb | 0x80000000u);   // order-preserving
      }
      key[i] = k;
      wave_hist_add(k >> 24, hist, lane);
    }
    __syncthreads();
    if (tid < 64) pivot_scan(hist, S, tid);
    __syncthreads();
    // S2: emit winners + collect pivot-bucket candidates (1 atomic/wave)
    {
      const unsigned pb = S[1];
#pragma unroll
      for (int j = 0; j < 8; ++j) {
        int i = j * 1024 + tid;
        unsigned by = key[i] >> 24;
        bool win = (by > pb), eq = (by == pb);
        unsigned pw = wave_claim(win, &S[2], lane);
        if (win) { tok[e * CAP + pw] = i; taken[i] = 1; }
        unsigned pc = wave_claim(eq, &S[4], lane);
        if (eq) candA[pc] = (unsigned short)i;
      }
    }
    __syncthreads();
    // refine 3 byte-levels on candidates (block-wide, barriers as in R11)
    unsigned short* cur = candA;
    unsigned short* nxt = candB;
    for (int shift = 16; shift >= 0; shift -= 8) {
      const unsigned m = S[4];
      __syncthreads();
      if (tid < 256) hist[tid] = 0;
      if (tid == 0) S[4] = 0;
      __syncthreads();
      for (unsigned q = tid; q < m; q += 1024)
        wave_hist_add((key[cur[q]] >> shift) & 255u, hist, lane);
      __syncthreads();
      if (tid < 64) pivot_scan(hist, S, tid);
      __syncthreads();
      const unsigned pb = S[1];
      for (unsigned q = tid; q < m; q += 1024) {
        unsigned i = cur[q];
        unsigned by = (key[i] >> shift) & 255u;
        bool win = (by > pb), eq = (by == pb);
        unsigned pw = wave_claim(win, &S[2], lane);
        if (win) { tok[e * CAP + pw] = (int)i; taken[i] = 1; }
        unsigned pc = wave_claim(eq, &S[4], lane);
        if (eq) nxt[pc] = (unsigned short)i;
      }
      __syncthreads();
      unsigned short* tmp = cur; cur = nxt; nxt = tmp;
    }
    // ties: exactly-pivot keys; take S[0] of them by LOWEST token index
    if (tid < 256) bmap[tid] = 0;
    __syncthreads();
    {
      const unsigned m = S[4];
      for (unsigned q = tid; q < m; q += 1024) {
        unsigned i = cur[q];
        atomicOr(&bmap[i >> 5], 1u << (i & 31));
      }
    }
    __syncthreads();
    if (tid < 64) tie_select(bmap, S, tok + e * CAP, taken, tid);
    __syncthreads();
  }
}

// ---- fat kernel: block 0 = assignment; blocks 1.. = weight transpose -------
__global__ __launch_bounds__(1024) void fat_assign_transpose(
    const float* __restrict__ scores, int* __restrict__ tok,
    const float* __restrict__ w1, const float* __restrict__ w2,
    unsigned short* __restrict__ w1T, unsigned short* __restrict__ w2T) {
  __shared__ __align__(16) char smem[77824];
  if (blockIdx.x == 0) { assign_body(scores, tok, smem); return; }
  const int tix = blockIdx.x - 1;
  const int which = tix >> 11;           // 2048 tiles each
  const int r = tix & 2047;
  const int e = r >> 8;
  const int rr = r & 255;
  int K, N, nt, kt;
  const float* s;
  unsigned short* d;
  if (which == 0) { K = DM; N = FF; nt = rr & 31; kt = rr >> 5; s = w1; d = w1T; }
  else            { K = FF; N = DM; nt = rr & 7;  kt = rr >> 3; s = w2; d = w2T; }
  s += (size_t)e * K * N;
  d += (size_t)e * N * K;
  const int q = threadIdx.x >> 8, t2 = threadIdx.x & 255;
  const int k0 = kt * 128 + (q >> 1) * 64;
  const int n0 = nt * 128 + (q & 1) * 64;
  float (*t)[65] = (float (*)[65])(smem + q * 16640);
  for (int p = t2; p < 1024; p += 256) {
    int rw = p >> 4, c4 = (p & 15) * 4;
    float4 v = *(const float4*)(s + (size_t)(k0 + rw) * N + n0 + c4);
    t[c4 + 0][rw] = v.x; t[c4 + 1][rw] = v.y;
    t[c4 + 2][rw] = v.z; t[c4 + 3][rw] = v.w;
  }
  __syncthreads();
  for (int p = t2; p < 512; p += 256) {
    int c = p >> 3, r8 = (p & 7) * 8;
    unsigned short tmp[8];
#pragma unroll
    for (int i = 0; i < 8; ++i) tmp[i] = f2bf(t[c][r8 + i]);
    *(uint4*)(d + (size_t)(n0 + c) * K + k0 + r8) = *(const uint4*)tmp;
  }
}

// ------- BK=32 3-slot-ring MFMA GEMM (unchanged from R11) -------------------
template <int EPI, bool GATHER, int K, int N, int BM, int BN, int TPB,
          int WM, int WN>
__global__ __launch_bounds__(TPB, 2) void gemm_ring(
    const unsigned short* __restrict__ A, const unsigned short* __restrict__ Bt,
    const float* __restrict__ bias, const int* __restrict__ tok,
    const float* __restrict__ xres, void* __restrict__ Cout) {
  constexpr int NT  = K / 32;
  constexpr int RM  = BM / WM, RN = BN / WN;
  constexpr int MR  = RM / 16, NR = RN / 16;
  constexpr int ALD = (BM * 32) / (8 * TPB);
  constexpr int BLD = (BN * 32) / (8 * TPB);
  constexpr int LD  = ALD + BLD;
  constexpr int SLOT = (BM + BN) * 32;
  __shared__ __align__(16) unsigned short lds[3 * SLOT];
  __shared__ int tokl[BM];

  const int flat = blockIdx.x + gridDim.x * (blockIdx.y + gridDim.y * blockIdx.z);
  const int nwg = gridDim.x * gridDim.y * gridDim.z;
  const int nf = (flat & 7) * (nwg >> 3) + (flat >> 3);
  const int bx = nf % gridDim.x;
  const int rem = nf / gridDim.x;
  const int e  = rem / gridDim.y;
  const int n0 = bx * BN, m0 = (rem % gridDim.y) * BM;

  const int tid = threadIdx.x, lane = tid & 63, w = tid >> 6;
  const int wr = w / WN, wc = w % WN;
  const int lr = lane & 15, lk = lane >> 4;

  for (int i = tid; i < BM; i += TPB) tokl[i] = tok[e * CAP + m0 + i];
  __syncthreads();

  const unsigned short* aptr[ALD];
  const unsigned short* bptr[BLD];
  const unsigned short* Be = Bt + (size_t)e * N * K + (size_t)n0 * K;
#pragma unroll
  for (int i = 0; i < ALD; ++i) {
    int c = i * TPB + tid, row = c >> 2, sp = c & 3;
    int s = sp ^ ((row >> 1) & 3);
    size_t grow = GATHER ? (size_t)tokl[row] : (size_t)(e * CAP + m0 + row);
    aptr[i] = A + grow * K + s * 8;
  }
#pragma unroll
  for (int i = 0; i < BLD; ++i) {
    int c = i * TPB + tid, row = c >> 2, sp = c & 3;
    int s = sp ^ ((row >> 1) & 3);
    bptr[i] = Be + (size_t)row * K + s * 8;
  }
  auto stage = [&](int tile, int slot) {
    unsigned short* base = lds + (size_t)slot * SLOT;
#pragma unroll
    for (int i = 0; i < ALD; ++i)
      gload_lds16(aptr[i] + tile * 32, base + (i * TPB + tid) * 8);
#pragma unroll
    for (int i = 0; i < BLD; ++i)
      gload_lds16(bptr[i] + tile * 32, base + BM * 32 + (i * TPB + tid) * 8);
  };

  const int swz = (lr >> 1) & 3;
  const int afo = (wr * RM + lr) * 32 + (lk ^ swz) * 8;
  const int bfo = BM * 32 + (wc * RN + lr) * 32 + (lk ^ swz) * 8;

  f32x4 acc[MR][NR] = {};

  stage(0, 0); stage(1, 1);
  asm volatile("s_waitcnt vmcnt(%0)" :: "i"(LD) : "memory");
  __builtin_amdgcn_s_barrier();

  int slot = 0;
#pragma unroll 1
  for (int t = 0; t < NT; ++t) {
    const unsigned short* base = lds + (size_t)slot * SLOT;
    bf16x8 af[MR], bfr[NR];
#pragma unroll
    for (int mi = 0; mi < MR; ++mi)
      af[mi] = *(const bf16x8*)(base + afo + mi * 512);
#pragma unroll
    for (int ni = 0; ni < NR; ++ni)
      bfr[ni] = *(const bf16x8*)(base + bfo + ni * 512);
    if (t + 2 < NT) {
      int dst = slot - 1;                   // (t+2)%3 == (t-1)%3
      if (dst < 0) dst = 2;
      stage(t + 2, dst);
      asm volatile("s_waitcnt vmcnt(%0)" :: "i"(LD) : "memory");
    } else if (t + 2 == NT) {
      asm volatile("s_waitcnt vmcnt(0)" ::: "memory");   // peel: fence t+1
    }
    __builtin_amdgcn_s_barrier();
    asm volatile("s_waitcnt lgkmcnt(0)" ::: "memory");
    __builtin_amdgcn_sched_barrier(0);
    __builtin_amdgcn_s_setprio(1);
#pragma unroll
    for (int mi = 0; mi < MR; ++mi)
#pragma unroll
      for (int ni = 0; ni < NR; ++ni)
        acc[mi][ni] = __builtin_amdgcn_mfma_f32_16x16x32_bf16(
            af[mi], bfr[ni], acc[mi][ni], 0, 0, 0);
    __builtin_amdgcn_s_setprio(0);
    __builtin_amdgcn_s_barrier();
    slot = (slot == 2) ? 0 : slot + 1;
  }

  const int lg = lane >> 4;
#pragma unroll
  for (int ni = 0; ni < NR; ++ni) {
    const int n = n0 + wc * RN + ni * 16 + lr;
    const float bb = bias[e * N + n];
#pragma unroll
    for (int mi = 0; mi < MR; ++mi) {
#pragma unroll
      for (int r = 0; r < 4; ++r) {
        const int ml = wr * RM + mi * 16 + lg * 4 + r;
        float v = acc[mi][ni][r] + bb;
        if (EPI == 1) {
          float z = 1.5957691216f * v + 0.07135481283f * v * v * v;
          float gl = v / (1.0f + __expf(-z));
          ((unsigned short*)Cout)[(size_t)(e * CAP + m0 + ml) * N + n] = f2bf(gl);
        } else {
          const int token = tokl[ml];
          v += xres[(size_t)token * DM + n];
          ((float*)Cout)[(size_t)token * (size_t)N + n] = v;
        }
      }
    }
  }
}

// ---------------- launch ----------------------------------------------------
extern "C" void kernel_launch(void* const* d_in, const int* in_sizes, int n_in,
                              void* d_out, int out_size, void* d_ws, size_t ws_size,
                              hipStream_t stream) {
  const float* x    = (const float*)d_in[0];
  const float* cent = (const float*)d_in[1];
  const float* ln_g = (const float*)d_in[2];
  const float* ln_b = (const float*)d_in[3];
  const float* w1   = (const float*)d_in[4];
  const float* b1   = (const float*)d_in[5];
  const float* w2   = (const float*)d_in[6];
  const float* b2   = (const float*)d_in[7];
  float* out = (float*)d_out;

  char* ws = (char*)d_ws;
  size_t off = 0;
  unsigned short* w1T = (unsigned short*)(ws + off); off += (size_t)NE * FF * DM * 2;
  unsigned short* w2T = (unsigned short*)(ws + off); off += (size_t)NE * DM * FF * 2;
  unsigned short* nrm = (unsigned short*)(ws + off); off += (size_t)T_TOK * DM * 2;
  unsigned short* h1  = (unsigned short*)(ws + off); off += (size_t)T_TOK * FF * 2;
  float* scores       = (float*)(ws + off);          off += (size_t)NE * T_TOK * 4;
  int* tok            = (int*)(ws + off);            off += (size_t)T_TOK * 4;

  ln_scores_k<<<dim3(T_TOK), 256, 0, stream>>>(x, ln_g, ln_b, cent, nrm, scores);
  fat_assign_transpose<<<dim3(1 + 4096), 1024, 0, stream>>>(
      scores, tok, w1, w2, w1T, w2T);
  gemm_ring<1, true, DM, FF, 256, 128, 512, 4, 2>
      <<<dim3(FF / 128, CAP / 256, NE), 512, 0, stream>>>(nrm, w1T, b1, tok, nullptr, h1);
  gemm_ring<2, false, FF, DM, 128, 128, 256, 2, 2>
      <<<dim3(DM / 128, CAP / 128, NE), 256, 0, stream>>>(h1, w2T, b2, tok, x, out);
}

// Round 14
// 332.931 us; speedup vs baseline: 1.4668x; 1.4668x over previous
//
#include <hip/hip_runtime.h>
#include <hip/hip_bf16.h>
#include <stdint.h>

// BaseLayer MoE block. I/O f32, GEMMs bf16 MFMA. T=8192, D=1024, F=4096, E=8.
// R14: assign reverted to R11's proven block-wide structure + free-list
// compaction (sweeps shrink 8192->1024 across experts; deterministic
// ballot-prefix compaction, no new atomic patterns). taken[] replaced by
// appending refine-losers/unselected-ties to the next free list.
// GEMMs (BK=32 ring), fat wrapper, ln_scores: R11-verbatim.

#define T_TOK 8192
#define DM    1024
#define FF    4096
#define NE    8
#define CAP   1024

typedef __attribute__((ext_vector_type(8))) __bf16 bf16x8;
typedef __attribute__((ext_vector_type(4))) float  f32x4;

__device__ __forceinline__ unsigned short f2bf(float f) {
  unsigned u = __float_as_uint(f);
  u += 0x7FFFu + ((u >> 16) & 1u);   // round-to-nearest-even
  return (unsigned short)(u >> 16);
}
__device__ __forceinline__ float keyf(float s) {
  // order-preserving map f32 -> u32 (as unsigned compare)
  return s;
}
__device__ __forceinline__ unsigned keyu(float s) {
  unsigned bb = __float_as_uint(s);
  return (bb & 0x80000000u) ? ~bb : (bb | 0x80000000u);
}
__device__ __forceinline__ void gload_lds16(const void* g, void* l) {
  __builtin_amdgcn_global_load_lds(
      (const __attribute__((address_space(1))) unsigned int*)(uintptr_t)g,
      (__attribute__((address_space(3))) unsigned int*)l, 16, 0, 0);
}

// ---------------- LN + centroid scores (scores stored [E][T]) ---------------
__global__ __launch_bounds__(256) void ln_scores_k(
    const float* __restrict__ x, const float* __restrict__ g,
    const float* __restrict__ b, const float* __restrict__ cent,
    unsigned short* __restrict__ nrm, float* __restrict__ scores) {
  const int t = blockIdx.x, tid = threadIdx.x;
  const int lane = tid & 63, w = tid >> 6;
  float4 v = ((const float4*)(x + (size_t)t * DM))[tid];
  float f0 = v.x, f1 = v.y, f2 = v.z, f3 = v.w;
  float s = f0 + f1 + f2 + f3;
  float sq = f0 * f0 + f1 * f1 + f2 * f2 + f3 * f3;
#pragma unroll
  for (int o = 32; o > 0; o >>= 1) { s += __shfl_xor(s, o); sq += __shfl_xor(sq, o); }
  __shared__ float red[8];
  if (lane == 0) { red[w] = s; red[4 + w] = sq; }
  __syncthreads();
  float S = red[0] + red[1] + red[2] + red[3];
  float SQ = red[4] + red[5] + red[6] + red[7];
  float mu = S * (1.0f / DM);
  float var = SQ * (1.0f / DM) - mu * mu;
  float rstd = rsqrtf(var + 1e-5f);
  float4 gv = ((const float4*)g)[tid];
  float4 bv = ((const float4*)b)[tid];
  float n0 = (f0 - mu) * rstd * gv.x + bv.x;
  float n1 = (f1 - mu) * rstd * gv.y + bv.y;
  float n2 = (f2 - mu) * rstd * gv.z + bv.z;
  float n3 = (f3 - mu) * rstd * gv.w + bv.w;
  ushort4 o4;
  o4.x = f2bf(n0); o4.y = f2bf(n1); o4.z = f2bf(n2); o4.w = f2bf(n3);
  ((ushort4*)(nrm + (size_t)t * DM))[tid] = o4;
  __shared__ float sred[4];
  for (int e = 0; e < NE; ++e) {
    float4 cv = ((const float4*)(cent + e * DM))[tid];
    float p = n0 * cv.x + n1 * cv.y + n2 * cv.z + n3 * cv.w;
#pragma unroll
    for (int o = 32; o > 0; o >>= 1) p += __shfl_xor(p, o);
    if (lane == 0) sred[w] = p;
    __syncthreads();
    if (tid == 0) scores[(size_t)e * T_TOK + t] = sred[0] + sred[1] + sred[2] + sred[3];
    __syncthreads();
  }
}

// ---- wave-0 helpers --------------------------------------------------------
// Suffix-scan hist[256] (4 buckets/lane): find pivot bucket; S[0]=need io.
__device__ __forceinline__ void pivot_scan(const unsigned* hist, unsigned* S,
                                           int l) {
  unsigned v0 = hist[4 * l], v1 = hist[4 * l + 1];
  unsigned v2 = hist[4 * l + 2], v3 = hist[4 * l + 3];
  unsigned own = v0 + v1 + v2 + v3;
  unsigned s = own;
#pragma unroll
  for (int off = 1; off < 64; off <<= 1) {
    unsigned t = __shfl_down(s, off);
    if (l + off < 64) s += t;
  }
  unsigned i3 = (s - own) + v3;
  unsigned i2 = i3 + v2;
  unsigned i1 = i2 + v1;
  unsigned i0 = i1 + v0;
  unsigned need = S[0];
  if (i0 >= need && i0 - v0 < need) { S[1] = 4 * l + 0; S[0] = need - (i0 - v0); }
  if (i1 >= need && i1 - v1 < need) { S[1] = 4 * l + 1; S[0] = need - (i1 - v1); }
  if (i2 >= need && i2 - v2 < need) { S[1] = 4 * l + 2; S[0] = need - (i2 - v2); }
  if (i3 >= need && i3 - v3 < need) { S[1] = 4 * l + 3; S[0] = need - (i3 - v3); }
}
// Walk bitmap (8192 bits): first S[0] set bits (lowest index) -> tok via S[2];
// the rest -> next free list via S[5].
__device__ __forceinline__ void tie_select(const unsigned* bmap, unsigned* S,
                                           int* tokdst, unsigned short* nfl,
                                           int l) {
  unsigned wds[4] = {bmap[4 * l], bmap[4 * l + 1], bmap[4 * l + 2], bmap[4 * l + 3]};
  unsigned cnt = __popc(wds[0]) + __popc(wds[1]) + __popc(wds[2]) + __popc(wds[3]);
  unsigned p = cnt;
#pragma unroll
  for (int off = 1; off < 64; off <<= 1) {
    unsigned t = __shfl_up(p, off);
    if (l >= off) p += t;
  }
  unsigned base = p - cnt;                 // exclusive prefix of set-bit counts
  const unsigned r = S[0];
#pragma unroll
  for (int c = 0; c < 4; ++c) {
    unsigned word = wds[c];
    while (word) {
      int b = __ffs(word) - 1; word &= word - 1;
      int i = (4 * l + c) * 32 + b;
      if (base < r) { unsigned pp = atomicAdd(&S[2], 1u); tokdst[pp] = i; }
      else          { unsigned pp = atomicAdd(&S[5], 1u); nfl[pp] = (unsigned short)i; }
      ++base;
    }
  }
}

// ---- assignment body: greedy per-expert exact top-C over a free list -------
__device__ void assign_body(const float* __restrict__ scores,
                            int* __restrict__ tok, char* smem) {
  unsigned short* flA   = (unsigned short*)smem;             // 16 KB
  unsigned short* flB   = (unsigned short*)(smem + 16384);   // 16 KB
  unsigned short* candA = (unsigned short*)(smem + 32768);   // 16 KB
  unsigned short* candB = (unsigned short*)(smem + 49152);   // 16 KB
  unsigned*       hist  = (unsigned*)(smem + 65536);         //  1 KB
  unsigned*       bmap  = (unsigned*)(smem + 66560);         //  1 KB
  unsigned*       wcnt  = (unsigned*)(smem + 67584);         //  64 B
  unsigned*       S     = (unsigned*)(smem + 67648);         // scalars
  const int tid = threadIdx.x, lane = tid & 63, wv = tid >> 6;
  unsigned short* fl = flA;
  unsigned short* nfl = flB;
  for (int i = tid; i < T_TOK; i += 1024) fl[i] = (unsigned short)i;
  unsigned fc = T_TOK;
  __syncthreads();
  for (int e = 0; e < NE; ++e) {
    const float* se = scores + (size_t)e * T_TOK;
    if (tid < 256) hist[tid] = 0;
    if (tid == 0) { S[0] = CAP; S[2] = 0; S[4] = 0; S[5] = 0; }
    __syncthreads();
    // S1: level-0 histogram over free tokens (per-lane atomics: R11-proven)
    for (unsigned q = tid; q < fc; q += 1024)
      atomicAdd(&hist[keyu(se[fl[q]]) >> 24], 1u);
    __syncthreads();
    if (tid < 64) pivot_scan(hist, S, tid);
    __syncthreads();
    const unsigned pb0 = S[1];
    // S2: emit winners / collect candidates / compact survivors (determin.)
    unsigned nbase = 0;
    const unsigned nch = (fc + 1023) >> 10;
    for (unsigned ch = 0; ch < nch; ++ch) {
      const unsigned q = ch * 1024 + tid;
      int i = -1; unsigned by = 0;
      if (q < fc) { i = fl[q]; by = keyu(se[i]) >> 24; }
      const bool win = (i >= 0) && (by > pb0);
      const bool eq  = (i >= 0) && (by == pb0);
      const bool sur = (i >= 0) && (by < pb0);
      if (win) { unsigned p = atomicAdd(&S[2], 1u); tok[e * CAP + p] = i; }
      if (eq)  { unsigned p = atomicAdd(&S[4], 1u); candA[p] = (unsigned short)i; }
      unsigned long long sb = __ballot(sur);
      if (lane == 0) wcnt[wv] = (unsigned)__popcll(sb);
      __syncthreads();
      unsigned base = 0, tot = 0;
      for (int j = 0; j < 16; ++j) { unsigned u = wcnt[j]; tot += u; if (j < wv) base += u; }
      if (sur) {
        unsigned off = (unsigned)__popcll(sb & ((1ull << lane) - 1ull));
        nfl[nbase + base + off] = (unsigned short)i;
      }
      nbase += tot;
      __syncthreads();
    }
    if (tid == 0) S[5] = nbase;
    __syncthreads();
    // refine 3 byte-levels on candidates; losers -> next free list
    unsigned short* cur = candA;
    unsigned short* nxt = candB;
    for (int shift = 16; shift >= 0; shift -= 8) {
      const unsigned m = S[4];
      __syncthreads();
      if (tid < 256) hist[tid] = 0;
      if (tid == 0) S[4] = 0;
      __syncthreads();
      for (unsigned q = tid; q < m; q += 1024)
        atomicAdd(&hist[(keyu(se[cur[q]]) >> shift) & 255u], 1u);
      __syncthreads();
      if (tid < 64) pivot_scan(hist, S, tid);
      __syncthreads();
      const unsigned pb = S[1];
      for (unsigned q = tid; q < m; q += 1024) {
        unsigned i = cur[q];
        unsigned by = (keyu(se[i]) >> shift) & 255u;
        if (by > pb) {
          unsigned p = atomicAdd(&S[2], 1u); tok[e * CAP + p] = (int)i;
        } else if (by == pb) {
          unsigned p = atomicAdd(&S[4], 1u); nxt[p] = (unsigned short)i;
        } else {
          unsigned p = atomicAdd(&S[5], 1u); nfl[p] = (unsigned short)i;
        }
      }
      __syncthreads();
      unsigned short* tmp = cur; cur = nxt; nxt = tmp;
    }
    // ties: exactly-pivot keys; lowest index wins; rest -> free list
    if (tid < 256) bmap[tid] = 0;
    __syncthreads();
    {
      const unsigned m = S[4];
      for (unsigned q = tid; q < m; q += 1024) {
        unsigned i = cur[q];
        atomicOr(&bmap[i >> 5], 1u << (i & 31));
      }
    }
    __syncthreads();
    if (tid < 64) tie_select(bmap, S, tok + e * CAP, nfl, tid);
    __syncthreads();
    fc = S[5];
    unsigned short* tmp = fl; fl = nfl; nfl = tmp;
    __syncthreads();
  }
}

// ---- fat kernel: block 0 = assignment; blocks 1.. = weight transpose -------
__global__ __launch_bounds__(1024) void fat_assign_transpose(
    const float* __restrict__ scores, int* __restrict__ tok,
    const float* __restrict__ w1, const float* __restrict__ w2,
    unsigned short* __restrict__ w1T, unsigned short* __restrict__ w2T) {
  __shared__ __align__(16) char smem[77824];
  if (blockIdx.x == 0) { assign_body(scores, tok, smem); return; }
  const int tix = blockIdx.x - 1;
  const int which = tix >> 11;           // 2048 tiles each
  const int r = tix & 2047;
  const int e = r >> 8;
  const int rr = r & 255;
  int K, N, nt, kt;
  const float* s;
  unsigned short* d;
  if (which == 0) { K = DM; N = FF; nt = rr & 31; kt = rr >> 5; s = w1; d = w1T; }
  else            { K = FF; N = DM; nt = rr & 7;  kt = rr >> 3; s = w2; d = w2T; }
  s += (size_t)e * K * N;
  d += (size_t)e * N * K;
  const int q = threadIdx.x >> 8, t2 = threadIdx.x & 255;
  const int k0 = kt * 128 + (q >> 1) * 64;
  const int n0 = nt * 128 + (q & 1) * 64;
  float (*t)[65] = (float (*)[65])(smem + q * 16640);
  for (int p = t2; p < 1024; p += 256) {
    int rw = p >> 4, c4 = (p & 15) * 4;
    float4 v = *(const float4*)(s + (size_t)(k0 + rw) * N + n0 + c4);
    t[c4 + 0][rw] = v.x; t[c4 + 1][rw] = v.y;
    t[c4 + 2][rw] = v.z; t[c4 + 3][rw] = v.w;
  }
  __syncthreads();
  for (int p = t2; p < 512; p += 256) {
    int c = p >> 3, r8 = (p & 7) * 8;
    unsigned short tmp[8];
#pragma unroll
    for (int i = 0; i < 8; ++i) tmp[i] = f2bf(t[c][r8 + i]);
    *(uint4*)(d + (size_t)(n0 + c) * K + k0 + r8) = *(const uint4*)tmp;
  }
}

// ------- BK=32 3-slot-ring MFMA GEMM (unchanged from R11) -------------------
template <int EPI, bool GATHER, int K, int N, int BM, int BN, int TPB,
          int WM, int WN>
__global__ __launch_bounds__(TPB, 2) void gemm_ring(
    const unsigned short* __restrict__ A, const unsigned short* __restrict__ Bt,
    const float* __restrict__ bias, const int* __restrict__ tok,
    const float* __restrict__ xres, void* __restrict__ Cout) {
  constexpr int NT  = K / 32;
  constexpr int RM  = BM / WM, RN = BN / WN;
  constexpr int MR  = RM / 16, NR = RN / 16;
  constexpr int ALD = (BM * 32) / (8 * TPB);
  constexpr int BLD = (BN * 32) / (8 * TPB);
  constexpr int LD  = ALD + BLD;
  constexpr int SLOT = (BM + BN) * 32;
  __shared__ __align__(16) unsigned short lds[3 * SLOT];
  __shared__ int tokl[BM];

  const int flat = blockIdx.x + gridDim.x * (blockIdx.y + gridDim.y * blockIdx.z);
  const int nwg = gridDim.x * gridDim.y * gridDim.z;
  const int nf = (flat & 7) * (nwg >> 3) + (flat >> 3);
  const int bx = nf % gridDim.x;
  const int rem = nf / gridDim.x;
  const int e  = rem / gridDim.y;
  const int n0 = bx * BN, m0 = (rem % gridDim.y) * BM;

  const int tid = threadIdx.x, lane = tid & 63, w = tid >> 6;
  const int wr = w / WN, wc = w % WN;
  const int lr = lane & 15, lk = lane >> 4;

  for (int i = tid; i < BM; i += TPB) tokl[i] = tok[e * CAP + m0 + i];
  __syncthreads();

  const unsigned short* aptr[ALD];
  const unsigned short* bptr[BLD];
  const unsigned short* Be = Bt + (size_t)e * N * K + (size_t)n0 * K;
#pragma unroll
  for (int i = 0; i < ALD; ++i) {
    int c = i * TPB + tid, row = c >> 2, sp = c & 3;
    int s = sp ^ ((row >> 1) & 3);
    size_t grow = GATHER ? (size_t)tokl[row] : (size_t)(e * CAP + m0 + row);
    aptr[i] = A + grow * K + s * 8;
  }
#pragma unroll
  for (int i = 0; i < BLD; ++i) {
    int c = i * TPB + tid, row = c >> 2, sp = c & 3;
    int s = sp ^ ((row >> 1) & 3);
    bptr[i] = Be + (size_t)row * K + s * 8;
  }
  auto stage = [&](int tile, int slot) {
    unsigned short* base = lds + (size_t)slot * SLOT;
#pragma unroll
    for (int i = 0; i < ALD; ++i)
      gload_lds16(aptr[i] + tile * 32, base + (i * TPB + tid) * 8);
#pragma unroll
    for (int i = 0; i < BLD; ++i)
      gload_lds16(bptr[i] + tile * 32, base + BM * 32 + (i * TPB + tid) * 8);
  };

  const int swz = (lr >> 1) & 3;
  const int afo = (wr * RM + lr) * 32 + (lk ^ swz) * 8;
  const int bfo = BM * 32 + (wc * RN + lr) * 32 + (lk ^ swz) * 8;

  f32x4 acc[MR][NR] = {};

  stage(0, 0); stage(1, 1);
  asm volatile("s_waitcnt vmcnt(%0)" :: "i"(LD) : "memory");
  __builtin_amdgcn_s_barrier();

  int slot = 0;
#pragma unroll 1
  for (int t = 0; t < NT; ++t) {
    const unsigned short* base = lds + (size_t)slot * SLOT;
    bf16x8 af[MR], bfr[NR];
#pragma unroll
    for (int mi = 0; mi < MR; ++mi)
      af[mi] = *(const bf16x8*)(base + afo + mi * 512);
#pragma unroll
    for (int ni = 0; ni < NR; ++ni)
      bfr[ni] = *(const bf16x8*)(base + bfo + ni * 512);
    if (t + 2 < NT) {
      int dst = slot - 1;                   // (t+2)%3 == (t-1)%3
      if (dst < 0) dst = 2;
      stage(t + 2, dst);
      asm volatile("s_waitcnt vmcnt(%0)" :: "i"(LD) : "memory");
    } else if (t + 2 == NT) {
      asm volatile("s_waitcnt vmcnt(0)" ::: "memory");   // peel: fence t+1
    }
    __builtin_amdgcn_s_barrier();
    asm volatile("s_waitcnt lgkmcnt(0)" ::: "memory");
    __builtin_amdgcn_sched_barrier(0);
    __builtin_amdgcn_s_setprio(1);
#pragma unroll
    for (int mi = 0; mi < MR; ++mi)
#pragma unroll
      for (int ni = 0; ni < NR; ++ni)
        acc[mi][ni] = __builtin_amdgcn_mfma_f32_16x16x32_bf16(
            af[mi], bfr[ni], acc[mi][ni], 0, 0, 0);
    __builtin_amdgcn_s_setprio(0);
    __builtin_amdgcn_s_barrier();
    slot = (slot == 2) ? 0 : slot + 1;
  }

  const int lg = lane >> 4;
#pragma unroll
  for (int ni = 0; ni < NR; ++ni) {
    const int n = n0 + wc * RN + ni * 16 + lr;
    const float bb = bias[e * N + n];
#pragma unroll
    for (int mi = 0; mi < MR; ++mi) {
#pragma unroll
      for (int r = 0; r < 4; ++r) {
        const int ml = wr * RM + mi * 16 + lg * 4 + r;
        float v = acc[mi][ni][r] + bb;
        if (EPI == 1) {
          float z = 1.5957691216f * v + 0.07135481283f * v * v * v;
          float gl = v / (1.0f + __expf(-z));
          ((unsigned short*)Cout)[(size_t)(e * CAP + m0 + ml) * N + n] = f2bf(gl);
        } else {
          const int token = tokl[ml];
          v += xres[(size_t)token * DM + n];
          ((float*)Cout)[(size_t)token * (size_t)N + n] = v;
        }
      }
    }
  }
}

// ---------------- launch ----------------------------------------------------
extern "C" void kernel_launch(void* const* d_in, const int* in_sizes, int n_in,
                              void* d_out, int out_size, void* d_ws, size_t ws_size,
                              hipStream_t stream) {
  const float* x    = (const float*)d_in[0];
  const float* cent = (const float*)d_in[1];
  const float* ln_g = (const float*)d_in[2];
  const float* ln_b = (const float*)d_in[3];
  const float* w1   = (const float*)d_in[4];
  const float* b1   = (const float*)d_in[5];
  const float* w2   = (const float*)d_in[6];
  const float* b2   = (const float*)d_in[7];
  float* out = (float*)d_out;

  char* ws = (char*)d_ws;
  size_t off = 0;
  unsigned short* w1T = (unsigned short*)(ws + off); off += (size_t)NE * FF * DM * 2;
  unsigned short* w2T = (unsigned short*)(ws + off); off += (size_t)NE * DM * FF * 2;
  unsigned short* nrm = (unsigned short*)(ws + off); off += (size_t)T_TOK * DM * 2;
  unsigned short* h1  = (unsigned short*)(ws + off); off += (size_t)T_TOK * FF * 2;
  float* scores       = (float*)(ws + off);          off += (size_t)NE * T_TOK * 4;
  int* tok            = (int*)(ws + off);            off += (size_t)T_TOK * 4;

  ln_scores_k<<<dim3(T_TOK), 256, 0, stream>>>(x, ln_g, ln_b, cent, nrm, scores);
  fat_assign_transpose<<<dim3(1 + 4096), 1024, 0, stream>>>(
      scores, tok, w1, w2, w1T, w2T);
  gemm_ring<1, true, DM, FF, 256, 128, 512, 4, 2>
      <<<dim3(FF / 128, CAP / 256, NE), 512, 0, stream>>>(nrm, w1T, b1, tok, nullptr, h1);
  gemm_ring<2, false, FF, DM, 128, 128, 256, 2, 2>
      <<<dim3(DM / 128, CAP / 128, NE), 256, 0, stream>>>(h1, w2T, b2, tok, x, out);
}

// Round 16
// 310.408 us; speedup vs baseline: 1.5732x; 1.0726x over previous
//
#include <hip/hip_runtime.h>
#include <hip/hip_bf16.h>
#include <stdint.h>

// BaseLayer MoE block. I/O f32, GEMMs bf16 MFMA. T=8192, D=1024, F=4096, E=8.
// R16: R15's fused-phase assign with the P1 race fixed: h0 is zeroed in P2
// (where it is dead), NOT in P1 where wave 0's pivot_scan is still reading it.
// That race produced a stale pivot -> S[2] overflow -> OOB tok writes (R15
// core dump). All other folded zeroings verified dead-in-phase.
// GEMMs (BK=32 ring), transpose, ln_scores: R11-verbatim.

#define T_TOK 8192
#define DM    1024
#define FF    4096
#define NE    8
#define CAP   1024

typedef __attribute__((ext_vector_type(8))) __bf16 bf16x8;
typedef __attribute__((ext_vector_type(4))) float  f32x4;

__device__ __forceinline__ unsigned short f2bf(float f) {
  unsigned u = __float_as_uint(f);
  u += 0x7FFFu + ((u >> 16) & 1u);   // round-to-nearest-even
  return (unsigned short)(u >> 16);
}
__device__ __forceinline__ unsigned keyu(float s) {
  unsigned bb = __float_as_uint(s);
  return (bb & 0x80000000u) ? ~bb : (bb | 0x80000000u);  // order-preserving
}
__device__ __forceinline__ void gload_lds16(const void* g, void* l) {
  __builtin_amdgcn_global_load_lds(
      (const __attribute__((address_space(1))) unsigned int*)(uintptr_t)g,
      (__attribute__((address_space(3))) unsigned int*)l, 16, 0, 0);
}

// ---------------- LN + centroid scores (scores stored [E][T]) ---------------
__global__ __launch_bounds__(256) void ln_scores_k(
    const float* __restrict__ x, const float* __restrict__ g,
    const float* __restrict__ b, const float* __restrict__ cent,
    unsigned short* __restrict__ nrm, float* __restrict__ scores) {
  const int t = blockIdx.x, tid = threadIdx.x;
  const int lane = tid & 63, w = tid >> 6;
  float4 v = ((const float4*)(x + (size_t)t * DM))[tid];
  float f0 = v.x, f1 = v.y, f2 = v.z, f3 = v.w;
  float s = f0 + f1 + f2 + f3;
  float sq = f0 * f0 + f1 * f1 + f2 * f2 + f3 * f3;
#pragma unroll
  for (int o = 32; o > 0; o >>= 1) { s += __shfl_xor(s, o); sq += __shfl_xor(sq, o); }
  __shared__ float red[8];
  if (lane == 0) { red[w] = s; red[4 + w] = sq; }
  __syncthreads();
  float S = red[0] + red[1] + red[2] + red[3];
  float SQ = red[4] + red[5] + red[6] + red[7];
  float mu = S * (1.0f / DM);
  float var = SQ * (1.0f / DM) - mu * mu;
  float rstd = rsqrtf(var + 1e-5f);
  float4 gv = ((const float4*)g)[tid];
  float4 bv = ((const float4*)b)[tid];
  float n0 = (f0 - mu) * rstd * gv.x + bv.x;
  float n1 = (f1 - mu) * rstd * gv.y + bv.y;
  float n2 = (f2 - mu) * rstd * gv.z + bv.z;
  float n3 = (f3 - mu) * rstd * gv.w + bv.w;
  ushort4 o4;
  o4.x = f2bf(n0); o4.y = f2bf(n1); o4.z = f2bf(n2); o4.w = f2bf(n3);
  ((ushort4*)(nrm + (size_t)t * DM))[tid] = o4;
  __shared__ float sred[4];
  for (int e = 0; e < NE; ++e) {
    float4 cv = ((const float4*)(cent + e * DM))[tid];
    float p = n0 * cv.x + n1 * cv.y + n2 * cv.z + n3 * cv.w;
#pragma unroll
    for (int o = 32; o > 0; o >>= 1) p += __shfl_xor(p, o);
    if (lane == 0) sred[w] = p;
    __syncthreads();
    if (tid == 0) scores[(size_t)e * T_TOK + t] = sred[0] + sred[1] + sred[2] + sred[3];
    __syncthreads();
  }
}

// ---- wave-0 helpers --------------------------------------------------------
__device__ __forceinline__ void pivot_scan(const unsigned* hist, unsigned* S,
                                           int l) {
  unsigned v0 = hist[4 * l], v1 = hist[4 * l + 1];
  unsigned v2 = hist[4 * l + 2], v3 = hist[4 * l + 3];
  unsigned own = v0 + v1 + v2 + v3;
  unsigned s = own;
#pragma unroll
  for (int off = 1; off < 64; off <<= 1) {
    unsigned t = __shfl_down(s, off);
    if (l + off < 64) s += t;
  }
  unsigned i3 = (s - own) + v3;
  unsigned i2 = i3 + v2;
  unsigned i1 = i2 + v1;
  unsigned i0 = i1 + v0;
  unsigned need = S[0];
  if (i0 >= need && i0 - v0 < need) { S[1] = 4 * l + 0; S[0] = need - (i0 - v0); }
  if (i1 >= need && i1 - v1 < need) { S[1] = 4 * l + 1; S[0] = need - (i1 - v1); }
  if (i2 >= need && i2 - v2 < need) { S[1] = 4 * l + 2; S[0] = need - (i2 - v2); }
  if (i3 >= need && i3 - v3 < need) { S[1] = 4 * l + 3; S[0] = need - (i3 - v3); }
}
__device__ __forceinline__ void tie_select(const unsigned* bmap, unsigned* S,
                                           int* tokdst, unsigned char* taken,
                                           int l) {
  unsigned wds[4] = {bmap[4 * l], bmap[4 * l + 1], bmap[4 * l + 2], bmap[4 * l + 3]};
  unsigned cnt = __popc(wds[0]) + __popc(wds[1]) + __popc(wds[2]) + __popc(wds[3]);
  unsigned p = cnt;
#pragma unroll
  for (int off = 1; off < 64; off <<= 1) {
    unsigned t = __shfl_up(p, off);
    if (l >= off) p += t;
  }
  unsigned base = p - cnt;
  const unsigned r = S[0];
#pragma unroll
  for (int c = 0; c < 4; ++c) {
    unsigned word = wds[c];
    while (word && base < r) {
      int b = __ffs(word) - 1; word &= word - 1;
      int i = (4 * l + c) * 32 + b;
      unsigned pp = atomicAdd(&S[2], 1u);
      tokdst[pp] = i; taken[i] = 1;
      ++base;
    }
    base += __popc(word);
  }
}

// ---- assignment body v3 (race-fixed): fused-phase exact greedy top-C -------
__device__ void assign_body(const float* __restrict__ scores,
                            int* __restrict__ tok, char* smem) {
  unsigned*       key   = (unsigned*)smem;                   // 32 KB
  unsigned short* candA = (unsigned short*)(smem + 32768);   // 16 KB
  unsigned short* candB = (unsigned short*)(smem + 49152);   // 16 KB
  unsigned char*  taken = (unsigned char*)(smem + 65536);    //  8 KB
  unsigned*       h0    = (unsigned*)(smem + 73728);         //  1 KB
  unsigned*       h1    = (unsigned*)(smem + 74752);         //  1 KB
  unsigned*       h2    = (unsigned*)(smem + 75776);         //  1 KB
  unsigned*       h3    = (unsigned*)(smem + 76800);         //  1 KB
  unsigned*       bmap  = (unsigned*)(smem + 77824);         //  1 KB
  unsigned*       S     = (unsigned*)(smem + 78848);         // scalars
  const int tid = threadIdx.x;
  for (int i = tid; i < T_TOK; i += 1024) taken[i] = 0;
  if (tid < 256) h0[tid] = 0;
  __syncthreads();
  for (int e = 0; e < NE; ++e) {
    const float* se = scores + (size_t)e * T_TOK;
    if (tid == 0) { S[0] = CAP; S[2] = 0; S[4] = 0; }
    else if (tid >= 256 && tid < 512) h1[tid - 256] = 0;
    __syncthreads();                                          // B1
    // P0: keys (LDS) + level-0 histogram
#pragma unroll
    for (int j = 0; j < 8; ++j) {
      int i = j * 1024 + tid;
      unsigned k = taken[i] ? 0u : keyu(se[i]);
      key[i] = k;
      atomicAdd(&h0[k >> 24], 1u);
    }
    __syncthreads();                                          // B2
    // P1: pivot level 0; idle waves pre-zero h2 ONLY (h0 is live here!)
    if (tid < 64) pivot_scan(h0, S, tid);
    else if (tid >= 256 && tid < 512) h2[tid - 256] = 0;
    __syncthreads();                                          // B3
    // P2: zero h0 (dead now) + level-0 emit + fused level-1 histogram
    if (tid < 256) h0[tid] = 0;
    {
      const unsigned pb = S[1];
#pragma unroll
      for (int j = 0; j < 8; ++j) {
        int i = j * 1024 + tid;
        unsigned k = key[i];
        unsigned by = k >> 24;
        if (by > pb) {
          unsigned p = atomicAdd(&S[2], 1u);
          tok[e * CAP + p] = i; taken[i] = 1;
        } else if (by == pb) {
          unsigned q = atomicAdd(&S[4], 1u);
          candA[q] = (unsigned short)i;
          atomicAdd(&h1[(k >> 16) & 255u], 1u);
        }
      }
    }
    __syncthreads();                                          // B4
    // P3: pivot level 1; zero h3; reset candB counter
    if (tid < 64) pivot_scan(h1, S, tid);
    else if (tid == 64) S[5] = 0;
    else if (tid >= 256 && tid < 512) h3[tid - 256] = 0;
    __syncthreads();                                          // B5
    // P4: level-1 emit candA -> candB + fused level-2 histogram
    {
      const unsigned m = S[4], pb = S[1];
      for (unsigned q = tid; q < m; q += 1024) {
        unsigned i = candA[q];
        unsigned k = key[i];
        unsigned by = (k >> 16) & 255u;
        if (by > pb) {
          unsigned p = atomicAdd(&S[2], 1u);
          tok[e * CAP + p] = (int)i; taken[i] = 1;
        } else if (by == pb) {
          unsigned p = atomicAdd(&S[5], 1u);
          candB[p] = (unsigned short)i;
          atomicAdd(&h2[(k >> 8) & 255u], 1u);
        }
      }
    }
    __syncthreads();                                          // B6
    // P5: pivot level 2; reset candA counter
    if (tid < 64) pivot_scan(h2, S, tid);
    else if (tid == 64) S[4] = 0;
    __syncthreads();                                          // B7
    // P6: level-2 emit candB -> candA + fused level-3 histogram
    {
      const unsigned m = S[5], pb = S[1];
      for (unsigned q = tid; q < m; q += 1024) {
        unsigned i = candB[q];
        unsigned k = key[i];
        unsigned by = (k >> 8) & 255u;
        if (by > pb) {
          unsigned p = atomicAdd(&S[2], 1u);
          tok[e * CAP + p] = (int)i; taken[i] = 1;
        } else if (by == pb) {
          unsigned p = atomicAdd(&S[4], 1u);
          candA[p] = (unsigned short)i;
          atomicAdd(&h3[k & 255u], 1u);
        }
      }
    }
    __syncthreads();                                          // B8
    // P7: pivot level 3; zero bitmap
    if (tid < 64) pivot_scan(h3, S, tid);
    else if (tid >= 256 && tid < 512) bmap[tid - 256] = 0;
    __syncthreads();                                          // B9
    // P8: level-3 emit candA; exact-pivot -> bitmap
    {
      const unsigned m = S[4], pb = S[1];
      for (unsigned q = tid; q < m; q += 1024) {
        unsigned i = candA[q];
        unsigned by = key[i] & 255u;
        if (by > pb) {
          unsigned p = atomicAdd(&S[2], 1u);
          tok[e * CAP + p] = (int)i; taken[i] = 1;
        } else if (by == pb) {
          atomicOr(&bmap[i >> 5], 1u << (i & 31));
        }
      }
    }
    __syncthreads();                                          // B10
    // P9: ties - S[0] lowest-index pivot-ties win
    if (tid < 64) tie_select(bmap, S, tok + e * CAP, taken, tid);
    __syncthreads();                                          // B11
  }
}

// ---- fat kernel: block 0 = assignment; blocks 1.. = weight transpose -------
__global__ __launch_bounds__(1024) void fat_assign_transpose(
    const float* __restrict__ scores, int* __restrict__ tok,
    const float* __restrict__ w1, const float* __restrict__ w2,
    unsigned short* __restrict__ w1T, unsigned short* __restrict__ w2T) {
  __shared__ __align__(16) char smem[79872];
  if (blockIdx.x == 0) { assign_body(scores, tok, smem); return; }
  const int tix = blockIdx.x - 1;
  const int which = tix >> 11;           // 2048 tiles each
  const int r = tix & 2047;
  const int e = r >> 8;
  const int rr = r & 255;
  int K, N, nt, kt;
  const float* s;
  unsigned short* d;
  if (which == 0) { K = DM; N = FF; nt = rr & 31; kt = rr >> 5; s = w1; d = w1T; }
  else            { K = FF; N = DM; nt = rr & 7;  kt = rr >> 3; s = w2; d = w2T; }
  s += (size_t)e * K * N;
  d += (size_t)e * N * K;
  const int q = threadIdx.x >> 8, t2 = threadIdx.x & 255;
  const int k0 = kt * 128 + (q >> 1) * 64;
  const int n0 = nt * 128 + (q & 1) * 64;
  float (*t)[65] = (float (*)[65])(smem + q * 16640);
  for (int p = t2; p < 1024; p += 256) {
    int rw = p >> 4, c4 = (p & 15) * 4;
    float4 v = *(const float4*)(s + (size_t)(k0 + rw) * N + n0 + c4);
    t[c4 + 0][rw] = v.x; t[c4 + 1][rw] = v.y;
    t[c4 + 2][rw] = v.z; t[c4 + 3][rw] = v.w;
  }
  __syncthreads();
  for (int p = t2; p < 512; p += 256) {
    int c = p >> 3, r8 = (p & 7) * 8;
    unsigned short tmp[8];
#pragma unroll
    for (int i = 0; i < 8; ++i) tmp[i] = f2bf(t[c][r8 + i]);
    *(uint4*)(d + (size_t)(n0 + c) * K + k0 + r8) = *(const uint4*)tmp;
  }
}

// ------- BK=32 3-slot-ring MFMA GEMM (unchanged from R11) -------------------
template <int EPI, bool GATHER, int K, int N, int BM, int BN, int TPB,
          int WM, int WN>
__global__ __launch_bounds__(TPB, 2) void gemm_ring(
    const unsigned short* __restrict__ A, const unsigned short* __restrict__ Bt,
    const float* __restrict__ bias, const int* __restrict__ tok,
    const float* __restrict__ xres, void* __restrict__ Cout) {
  constexpr int NT  = K / 32;
  constexpr int RM  = BM / WM, RN = BN / WN;
  constexpr int MR  = RM / 16, NR = RN / 16;
  constexpr int ALD = (BM * 32) / (8 * TPB);
  constexpr int BLD = (BN * 32) / (8 * TPB);
  constexpr int LD  = ALD + BLD;
  constexpr int SLOT = (BM + BN) * 32;
  __shared__ __align__(16) unsigned short lds[3 * SLOT];
  __shared__ int tokl[BM];

  const int flat = blockIdx.x + gridDim.x * (blockIdx.y + gridDim.y * blockIdx.z);
  const int nwg = gridDim.x * gridDim.y * gridDim.z;
  const int nf = (flat & 7) * (nwg >> 3) + (flat >> 3);
  const int bx = nf % gridDim.x;
  const int rem = nf / gridDim.x;
  const int e  = rem / gridDim.y;
  const int n0 = bx * BN, m0 = (rem % gridDim.y) * BM;

  const int tid = threadIdx.x, lane = tid & 63, w = tid >> 6;
  const int wr = w / WN, wc = w % WN;
  const int lr = lane & 15, lk = lane >> 4;

  for (int i = tid; i < BM; i += TPB) tokl[i] = tok[e * CAP + m0 + i];
  __syncthreads();

  const unsigned short* aptr[ALD];
  const unsigned short* bptr[BLD];
  const unsigned short* Be = Bt + (size_t)e * N * K + (size_t)n0 * K;
#pragma unroll
  for (int i = 0; i < ALD; ++i) {
    int c = i * TPB + tid, row = c >> 2, sp = c & 3;
    int s = sp ^ ((row >> 1) & 3);
    size_t grow = GATHER ? (size_t)tokl[row] : (size_t)(e * CAP + m0 + row);
    aptr[i] = A + grow * K + s * 8;
  }
#pragma unroll
  for (int i = 0; i < BLD; ++i) {
    int c = i * TPB + tid, row = c >> 2, sp = c & 3;
    int s = sp ^ ((row >> 1) & 3);
    bptr[i] = Be + (size_t)row * K + s * 8;
  }
  auto stage = [&](int tile, int slot) {
    unsigned short* base = lds + (size_t)slot * SLOT;
#pragma unroll
    for (int i = 0; i < ALD; ++i)
      gload_lds16(aptr[i] + tile * 32, base + (i * TPB + tid) * 8);
#pragma unroll
    for (int i = 0; i < BLD; ++i)
      gload_lds16(bptr[i] + tile * 32, base + BM * 32 + (i * TPB + tid) * 8);
  };

  const int swz = (lr >> 1) & 3;
  const int afo = (wr * RM + lr) * 32 + (lk ^ swz) * 8;
  const int bfo = BM * 32 + (wc * RN + lr) * 32 + (lk ^ swz) * 8;

  f32x4 acc[MR][NR] = {};

  stage(0, 0); stage(1, 1);
  asm volatile("s_waitcnt vmcnt(%0)" :: "i"(LD) : "memory");
  __builtin_amdgcn_s_barrier();

  int slot = 0;
#pragma unroll 1
  for (int t = 0; t < NT; ++t) {
    const unsigned short* base = lds + (size_t)slot * SLOT;
    bf16x8 af[MR], bfr[NR];
#pragma unroll
    for (int mi = 0; mi < MR; ++mi)
      af[mi] = *(const bf16x8*)(base + afo + mi * 512);
#pragma unroll
    for (int ni = 0; ni < NR; ++ni)
      bfr[ni] = *(const bf16x8*)(base + bfo + ni * 512);
    if (t + 2 < NT) {
      int dst = slot - 1;                   // (t+2)%3 == (t-1)%3
      if (dst < 0) dst = 2;
      stage(t + 2, dst);
      asm volatile("s_waitcnt vmcnt(%0)" :: "i"(LD) : "memory");
    } else if (t + 2 == NT) {
      asm volatile("s_waitcnt vmcnt(0)" ::: "memory");   // peel: fence t+1
    }
    __builtin_amdgcn_s_barrier();
    asm volatile("s_waitcnt lgkmcnt(0)" ::: "memory");
    __builtin_amdgcn_sched_barrier(0);
    __builtin_amdgcn_s_setprio(1);
#pragma unroll
    for (int mi = 0; mi < MR; ++mi)
#pragma unroll
      for (int ni = 0; ni < NR; ++ni)
        acc[mi][ni] = __builtin_amdgcn_mfma_f32_16x16x32_bf16(
            af[mi], bfr[ni], acc[mi][ni], 0, 0, 0);
    __builtin_amdgcn_s_setprio(0);
    __builtin_amdgcn_s_barrier();
    slot = (slot == 2) ? 0 : slot + 1;
  }

  const int lg = lane >> 4;
#pragma unroll
  for (int ni = 0; ni < NR; ++ni) {
    const int n = n0 + wc * RN + ni * 16 + lr;
    const float bb = bias[e * N + n];
#pragma unroll
    for (int mi = 0; mi < MR; ++mi) {
#pragma unroll
      for (int r = 0; r < 4; ++r) {
        const int ml = wr * RM + mi * 16 + lg * 4 + r;
        float v = acc[mi][ni][r] + bb;
        if (EPI == 1) {
          float z = 1.5957691216f * v + 0.07135481283f * v * v * v;
          float gl = v / (1.0f + __expf(-z));
          ((unsigned short*)Cout)[(size_t)(e * CAP + m0 + ml) * N + n] = f2bf(gl);
        } else {
          const int token = tokl[ml];
          v += xres[(size_t)token * DM + n];
          ((float*)Cout)[(size_t)token * (size_t)N + n] = v;
        }
      }
    }
  }
}

// ---------------- launch ----------------------------------------------------
extern "C" void kernel_launch(void* const* d_in, const int* in_sizes, int n_in,
                              void* d_out, int out_size, void* d_ws, size_t ws_size,
                              hipStream_t stream) {
  const float* x    = (const float*)d_in[0];
  const float* cent = (const float*)d_in[1];
  const float* ln_g = (const float*)d_in[2];
  const float* ln_b = (const float*)d_in[3];
  const float* w1   = (const float*)d_in[4];
  const float* b1   = (const float*)d_in[5];
  const float* w2   = (const float*)d_in[6];
  const float* b2   = (const float*)d_in[7];
  float* out = (float*)d_out;

  char* ws = (char*)d_ws;
  size_t off = 0;
  unsigned short* w1T = (unsigned short*)(ws + off); off += (size_t)NE * FF * DM * 2;
  unsigned short* w2T = (unsigned short*)(ws + off); off += (size_t)NE * DM * FF * 2;
  unsigned short* nrm = (unsigned short*)(ws + off); off += (size_t)T_TOK * DM * 2;
  unsigned short* h1  = (unsigned short*)(ws + off); off += (size_t)T_TOK * FF * 2;
  float* scores       = (float*)(ws + off);          off += (size_t)NE * T_TOK * 4;
  int* tok            = (int*)(ws + off);            off += (size_t)T_TOK * 4;

  ln_scores_k<<<dim3(T_TOK), 256, 0, stream>>>(x, ln_g, ln_b, cent, nrm, scores);
  fat_assign_transpose<<<dim3(1 + 4096), 1024, 0, stream>>>(
      scores, tok, w1, w2, w1T, w2T);
  gemm_ring<1, true, DM, FF, 256, 128, 512, 4, 2>
      <<<dim3(FF / 128, CAP / 256, NE), 512, 0, stream>>>(nrm, w1T, b1, tok, nullptr, h1);
  gemm_ring<2, false, FF, DM, 128, 128, 256, 2, 2>
      <<<dim3(DM / 128, CAP / 128, NE), 256, 0, stream>>>(h1, w2T, b2, tok, x, out);
}

// Round 17
// 300.593 us; speedup vs baseline: 1.6246x; 1.0327x over previous
//
#include <hip/hip_runtime.h>
#include <hip/hip_bf16.h>
#include <stdint.h>

// BaseLayer MoE block. I/O f32, GEMMs bf16 MFMA. T=8192, D=1024, F=4096, E=8.
// R17: R16 + assign latency-hiding: P0 hoists all 8 score loads (uncond.)
// before key computation (breaks LDS->global serial chain), and P2 consumes
// the thread's own keys from registers (kreg[8]) instead of re-reading LDS.
// Phase/barrier structure byte-identical to R16 (310 us best).
// GEMMs (BK=32 ring), transpose, ln_scores: R11-verbatim.

#define T_TOK 8192
#define DM    1024
#define FF    4096
#define NE    8
#define CAP   1024

typedef __attribute__((ext_vector_type(8))) __bf16 bf16x8;
typedef __attribute__((ext_vector_type(4))) float  f32x4;

__device__ __forceinline__ unsigned short f2bf(float f) {
  unsigned u = __float_as_uint(f);
  u += 0x7FFFu + ((u >> 16) & 1u);   // round-to-nearest-even
  return (unsigned short)(u >> 16);
}
__device__ __forceinline__ unsigned keyu(float s) {
  unsigned bb = __float_as_uint(s);
  return (bb & 0x80000000u) ? ~bb : (bb | 0x80000000u);  // order-preserving
}
__device__ __forceinline__ void gload_lds16(const void* g, void* l) {
  __builtin_amdgcn_global_load_lds(
      (const __attribute__((address_space(1))) unsigned int*)(uintptr_t)g,
      (__attribute__((address_space(3))) unsigned int*)l, 16, 0, 0);
}

// ---------------- LN + centroid scores (scores stored [E][T]) ---------------
__global__ __launch_bounds__(256) void ln_scores_k(
    const float* __restrict__ x, const float* __restrict__ g,
    const float* __restrict__ b, const float* __restrict__ cent,
    unsigned short* __restrict__ nrm, float* __restrict__ scores) {
  const int t = blockIdx.x, tid = threadIdx.x;
  const int lane = tid & 63, w = tid >> 6;
  float4 v = ((const float4*)(x + (size_t)t * DM))[tid];
  float f0 = v.x, f1 = v.y, f2 = v.z, f3 = v.w;
  float s = f0 + f1 + f2 + f3;
  float sq = f0 * f0 + f1 * f1 + f2 * f2 + f3 * f3;
#pragma unroll
  for (int o = 32; o > 0; o >>= 1) { s += __shfl_xor(s, o); sq += __shfl_xor(sq, o); }
  __shared__ float red[8];
  if (lane == 0) { red[w] = s; red[4 + w] = sq; }
  __syncthreads();
  float S = red[0] + red[1] + red[2] + red[3];
  float SQ = red[4] + red[5] + red[6] + red[7];
  float mu = S * (1.0f / DM);
  float var = SQ * (1.0f / DM) - mu * mu;
  float rstd = rsqrtf(var + 1e-5f);
  float4 gv = ((const float4*)g)[tid];
  float4 bv = ((const float4*)b)[tid];
  float n0 = (f0 - mu) * rstd * gv.x + bv.x;
  float n1 = (f1 - mu) * rstd * gv.y + bv.y;
  float n2 = (f2 - mu) * rstd * gv.z + bv.z;
  float n3 = (f3 - mu) * rstd * gv.w + bv.w;
  ushort4 o4;
  o4.x = f2bf(n0); o4.y = f2bf(n1); o4.z = f2bf(n2); o4.w = f2bf(n3);
  ((ushort4*)(nrm + (size_t)t * DM))[tid] = o4;
  __shared__ float sred[4];
  for (int e = 0; e < NE; ++e) {
    float4 cv = ((const float4*)(cent + e * DM))[tid];
    float p = n0 * cv.x + n1 * cv.y + n2 * cv.z + n3 * cv.w;
#pragma unroll
    for (int o = 32; o > 0; o >>= 1) p += __shfl_xor(p, o);
    if (lane == 0) sred[w] = p;
    __syncthreads();
    if (tid == 0) scores[(size_t)e * T_TOK + t] = sred[0] + sred[1] + sred[2] + sred[3];
    __syncthreads();
  }
}

// ---- wave-0 helpers --------------------------------------------------------
__device__ __forceinline__ void pivot_scan(const unsigned* hist, unsigned* S,
                                           int l) {
  unsigned v0 = hist[4 * l], v1 = hist[4 * l + 1];
  unsigned v2 = hist[4 * l + 2], v3 = hist[4 * l + 3];
  unsigned own = v0 + v1 + v2 + v3;
  unsigned s = own;
#pragma unroll
  for (int off = 1; off < 64; off <<= 1) {
    unsigned t = __shfl_down(s, off);
    if (l + off < 64) s += t;
  }
  unsigned i3 = (s - own) + v3;
  unsigned i2 = i3 + v2;
  unsigned i1 = i2 + v1;
  unsigned i0 = i1 + v0;
  unsigned need = S[0];
  if (i0 >= need && i0 - v0 < need) { S[1] = 4 * l + 0; S[0] = need - (i0 - v0); }
  if (i1 >= need && i1 - v1 < need) { S[1] = 4 * l + 1; S[0] = need - (i1 - v1); }
  if (i2 >= need && i2 - v2 < need) { S[1] = 4 * l + 2; S[0] = need - (i2 - v2); }
  if (i3 >= need && i3 - v3 < need) { S[1] = 4 * l + 3; S[0] = need - (i3 - v3); }
}
__device__ __forceinline__ void tie_select(const unsigned* bmap, unsigned* S,
                                           int* tokdst, unsigned char* taken,
                                           int l) {
  unsigned wds[4] = {bmap[4 * l], bmap[4 * l + 1], bmap[4 * l + 2], bmap[4 * l + 3]};
  unsigned cnt = __popc(wds[0]) + __popc(wds[1]) + __popc(wds[2]) + __popc(wds[3]);
  unsigned p = cnt;
#pragma unroll
  for (int off = 1; off < 64; off <<= 1) {
    unsigned t = __shfl_up(p, off);
    if (l >= off) p += t;
  }
  unsigned base = p - cnt;
  const unsigned r = S[0];
#pragma unroll
  for (int c = 0; c < 4; ++c) {
    unsigned word = wds[c];
    while (word && base < r) {
      int b = __ffs(word) - 1; word &= word - 1;
      int i = (4 * l + c) * 32 + b;
      unsigned pp = atomicAdd(&S[2], 1u);
      tokdst[pp] = i; taken[i] = 1;
      ++base;
    }
    base += __popc(word);
  }
}

// ---- assignment body v4: fused-phase + hoisted loads + register keys -------
__device__ void assign_body(const float* __restrict__ scores,
                            int* __restrict__ tok, char* smem) {
  unsigned*       key   = (unsigned*)smem;                   // 32 KB
  unsigned short* candA = (unsigned short*)(smem + 32768);   // 16 KB
  unsigned short* candB = (unsigned short*)(smem + 49152);   // 16 KB
  unsigned char*  taken = (unsigned char*)(smem + 65536);    //  8 KB
  unsigned*       h0    = (unsigned*)(smem + 73728);         //  1 KB
  unsigned*       h1    = (unsigned*)(smem + 74752);         //  1 KB
  unsigned*       h2    = (unsigned*)(smem + 75776);         //  1 KB
  unsigned*       h3    = (unsigned*)(smem + 76800);         //  1 KB
  unsigned*       bmap  = (unsigned*)(smem + 77824);         //  1 KB
  unsigned*       S     = (unsigned*)(smem + 78848);         // scalars
  const int tid = threadIdx.x;
  for (int i = tid; i < T_TOK; i += 1024) taken[i] = 0;
  if (tid < 256) h0[tid] = 0;
  __syncthreads();
  for (int e = 0; e < NE; ++e) {
    const float* se = scores + (size_t)e * T_TOK;
    if (tid == 0) { S[0] = CAP; S[2] = 0; S[4] = 0; }
    else if (tid >= 256 && tid < 512) h1[tid - 256] = 0;
    __syncthreads();                                          // B1
    // P0: hoisted unconditional loads -> keys (regs + LDS) + level-0 hist
    unsigned kreg[8];
    {
      float sc[8];
      unsigned char tk[8];
#pragma unroll
      for (int j = 0; j < 8; ++j) sc[j] = se[j * 1024 + tid];   // 8 indep loads
#pragma unroll
      for (int j = 0; j < 8; ++j) tk[j] = taken[j * 1024 + tid];
#pragma unroll
      for (int j = 0; j < 8; ++j) {
        unsigned k = tk[j] ? 0u : keyu(sc[j]);
        kreg[j] = k;
        key[j * 1024 + tid] = k;
        atomicAdd(&h0[k >> 24], 1u);
      }
    }
    __syncthreads();                                          // B2
    // P1: pivot level 0; idle waves pre-zero h2 ONLY (h0 live here)
    if (tid < 64) pivot_scan(h0, S, tid);
    else if (tid >= 256 && tid < 512) h2[tid - 256] = 0;
    __syncthreads();                                          // B3
    // P2: zero h0 (dead) + level-0 emit from REGISTER keys + fused h1
    if (tid < 256) h0[tid] = 0;
    {
      const unsigned pb = S[1];
#pragma unroll
      for (int j = 0; j < 8; ++j) {
        int i = j * 1024 + tid;
        unsigned k = kreg[j];
        unsigned by = k >> 24;
        if (by > pb) {
          unsigned p = atomicAdd(&S[2], 1u);
          tok[e * CAP + p] = i; taken[i] = 1;
        } else if (by == pb) {
          unsigned q = atomicAdd(&S[4], 1u);
          candA[q] = (unsigned short)i;
          atomicAdd(&h1[(k >> 16) & 255u], 1u);
        }
      }
    }
    __syncthreads();                                          // B4
    // P3: pivot level 1; zero h3; reset candB counter
    if (tid < 64) pivot_scan(h1, S, tid);
    else if (tid == 64) S[5] = 0;
    else if (tid >= 256 && tid < 512) h3[tid - 256] = 0;
    __syncthreads();                                          // B5
    // P4: level-1 emit candA -> candB + fused level-2 histogram
    {
      const unsigned m = S[4], pb = S[1];
      for (unsigned q = tid; q < m; q += 1024) {
        unsigned i = candA[q];
        unsigned k = key[i];
        unsigned by = (k >> 16) & 255u;
        if (by > pb) {
          unsigned p = atomicAdd(&S[2], 1u);
          tok[e * CAP + p] = (int)i; taken[i] = 1;
        } else if (by == pb) {
          unsigned p = atomicAdd(&S[5], 1u);
          candB[p] = (unsigned short)i;
          atomicAdd(&h2[(k >> 8) & 255u], 1u);
        }
      }
    }
    __syncthreads();                                          // B6
    // P5: pivot level 2; reset candA counter
    if (tid < 64) pivot_scan(h2, S, tid);
    else if (tid == 64) S[4] = 0;
    __syncthreads();                                          // B7
    // P6: level-2 emit candB -> candA + fused level-3 histogram
    {
      const unsigned m = S[5], pb = S[1];
      for (unsigned q = tid; q < m; q += 1024) {
        unsigned i = candB[q];
        unsigned k = key[i];
        unsigned by = (k >> 8) & 255u;
        if (by > pb) {
          unsigned p = atomicAdd(&S[2], 1u);
          tok[e * CAP + p] = (int)i; taken[i] = 1;
        } else if (by == pb) {
          unsigned p = atomicAdd(&S[4], 1u);
          candA[p] = (unsigned short)i;
          atomicAdd(&h3[k & 255u], 1u);
        }
      }
    }
    __syncthreads();                                          // B8
    // P7: pivot level 3; zero bitmap
    if (tid < 64) pivot_scan(h3, S, tid);
    else if (tid >= 256 && tid < 512) bmap[tid - 256] = 0;
    __syncthreads();                                          // B9
    // P8: level-3 emit candA; exact-pivot -> bitmap
    {
      const unsigned m = S[4], pb = S[1];
      for (unsigned q = tid; q < m; q += 1024) {
        unsigned i = candA[q];
        unsigned by = key[i] & 255u;
        if (by > pb) {
          unsigned p = atomicAdd(&S[2], 1u);
          tok[e * CAP + p] = (int)i; taken[i] = 1;
        } else if (by == pb) {
          atomicOr(&bmap[i >> 5], 1u << (i & 31));
        }
      }
    }
    __syncthreads();                                          // B10
    // P9: ties - S[0] lowest-index pivot-ties win
    if (tid < 64) tie_select(bmap, S, tok + e * CAP, taken, tid);
    __syncthreads();                                          // B11
  }
}

// ---- fat kernel: block 0 = assignment; blocks 1.. = weight transpose -------
__global__ __launch_bounds__(1024) void fat_assign_transpose(
    const float* __restrict__ scores, int* __restrict__ tok,
    const float* __restrict__ w1, const float* __restrict__ w2,
    unsigned short* __restrict__ w1T, unsigned short* __restrict__ w2T) {
  __shared__ __align__(16) char smem[79872];
  if (blockIdx.x == 0) { assign_body(scores, tok, smem); return; }
  const int tix = blockIdx.x - 1;
  const int which = tix >> 11;           // 2048 tiles each
  const int r = tix & 2047;
  const int e = r >> 8;
  const int rr = r & 255;
  int K, N, nt, kt;
  const float* s;
  unsigned short* d;
  if (which == 0) { K = DM; N = FF; nt = rr & 31; kt = rr >> 5; s = w1; d = w1T; }
  else            { K = FF; N = DM; nt = rr & 7;  kt = rr >> 3; s = w2; d = w2T; }
  s += (size_t)e * K * N;
  d += (size_t)e * N * K;
  const int q = threadIdx.x >> 8, t2 = threadIdx.x & 255;
  const int k0 = kt * 128 + (q >> 1) * 64;
  const int n0 = nt * 128 + (q & 1) * 64;
  float (*t)[65] = (float (*)[65])(smem + q * 16640);
  for (int p = t2; p < 1024; p += 256) {
    int rw = p >> 4, c4 = (p & 15) * 4;
    float4 v = *(const float4*)(s + (size_t)(k0 + rw) * N + n0 + c4);
    t[c4 + 0][rw] = v.x; t[c4 + 1][rw] = v.y;
    t[c4 + 2][rw] = v.z; t[c4 + 3][rw] = v.w;
  }
  __syncthreads();
  for (int p = t2; p < 512; p += 256) {
    int c = p >> 3, r8 = (p & 7) * 8;
    unsigned short tmp[8];
#pragma unroll
    for (int i = 0; i < 8; ++i) tmp[i] = f2bf(t[c][r8 + i]);
    *(uint4*)(d + (size_t)(n0 + c) * K + k0 + r8) = *(const uint4*)tmp;
  }
}

// ------- BK=32 3-slot-ring MFMA GEMM (unchanged from R11) -------------------
template <int EPI, bool GATHER, int K, int N, int BM, int BN, int TPB,
          int WM, int WN>
__global__ __launch_bounds__(TPB, 2) void gemm_ring(
    const unsigned short* __restrict__ A, const unsigned short* __restrict__ Bt,
    const float* __restrict__ bias, const int* __restrict__ tok,
    const float* __restrict__ xres, void* __restrict__ Cout) {
  constexpr int NT  = K / 32;
  constexpr int RM  = BM / WM, RN = BN / WN;
  constexpr int MR  = RM / 16, NR = RN / 16;
  constexpr int ALD = (BM * 32) / (8 * TPB);
  constexpr int BLD = (BN * 32) / (8 * TPB);
  constexpr int LD  = ALD + BLD;
  constexpr int SLOT = (BM + BN) * 32;
  __shared__ __align__(16) unsigned short lds[3 * SLOT];
  __shared__ int tokl[BM];

  const int flat = blockIdx.x + gridDim.x * (blockIdx.y + gridDim.y * blockIdx.z);
  const int nwg = gridDim.x * gridDim.y * gridDim.z;
  const int nf = (flat & 7) * (nwg >> 3) + (flat >> 3);
  const int bx = nf % gridDim.x;
  const int rem = nf / gridDim.x;
  const int e  = rem / gridDim.y;
  const int n0 = bx * BN, m0 = (rem % gridDim.y) * BM;

  const int tid = threadIdx.x, lane = tid & 63, w = tid >> 6;
  const int wr = w / WN, wc = w % WN;
  const int lr = lane & 15, lk = lane >> 4;

  for (int i = tid; i < BM; i += TPB) tokl[i] = tok[e * CAP + m0 + i];
  __syncthreads();

  const unsigned short* aptr[ALD];
  const unsigned short* bptr[BLD];
  const unsigned short* Be = Bt + (size_t)e * N * K + (size_t)n0 * K;
#pragma unroll
  for (int i = 0; i < ALD; ++i) {
    int c = i * TPB + tid, row = c >> 2, sp = c & 3;
    int s = sp ^ ((row >> 1) & 3);
    size_t grow = GATHER ? (size_t)tokl[row] : (size_t)(e * CAP + m0 + row);
    aptr[i] = A + grow * K + s * 8;
  }
#pragma unroll
  for (int i = 0; i < BLD; ++i) {
    int c = i * TPB + tid, row = c >> 2, sp = c & 3;
    int s = sp ^ ((row >> 1) & 3);
    bptr[i] = Be + (size_t)row * K + s * 8;
  }
  auto stage = [&](int tile, int slot) {
    unsigned short* base = lds + (size_t)slot * SLOT;
#pragma unroll
    for (int i = 0; i < ALD; ++i)
      gload_lds16(aptr[i] + tile * 32, base + (i * TPB + tid) * 8);
#pragma unroll
    for (int i = 0; i < BLD; ++i)
      gload_lds16(bptr[i] + tile * 32, base + BM * 32 + (i * TPB + tid) * 8);
  };

  const int swz = (lr >> 1) & 3;
  const int afo = (wr * RM + lr) * 32 + (lk ^ swz) * 8;
  const int bfo = BM * 32 + (wc * RN + lr) * 32 + (lk ^ swz) * 8;

  f32x4 acc[MR][NR] = {};

  stage(0, 0); stage(1, 1);
  asm volatile("s_waitcnt vmcnt(%0)" :: "i"(LD) : "memory");
  __builtin_amdgcn_s_barrier();

  int slot = 0;
#pragma unroll 1
  for (int t = 0; t < NT; ++t) {
    const unsigned short* base = lds + (size_t)slot * SLOT;
    bf16x8 af[MR], bfr[NR];
#pragma unroll
    for (int mi = 0; mi < MR; ++mi)
      af[mi] = *(const bf16x8*)(base + afo + mi * 512);
#pragma unroll
    for (int ni = 0; ni < NR; ++ni)
      bfr[ni] = *(const bf16x8*)(base + bfo + ni * 512);
    if (t + 2 < NT) {
      int dst = slot - 1;                   // (t+2)%3 == (t-1)%3
      if (dst < 0) dst = 2;
      stage(t + 2, dst);
      asm volatile("s_waitcnt vmcnt(%0)" :: "i"(LD) : "memory");
    } else if (t + 2 == NT) {
      asm volatile("s_waitcnt vmcnt(0)" ::: "memory");   // peel: fence t+1
    }
    __builtin_amdgcn_s_barrier();
    asm volatile("s_waitcnt lgkmcnt(0)" ::: "memory");
    __builtin_amdgcn_sched_barrier(0);
    __builtin_amdgcn_s_setprio(1);
#pragma unroll
    for (int mi = 0; mi < MR; ++mi)
#pragma unroll
      for (int ni = 0; ni < NR; ++ni)
        acc[mi][ni] = __builtin_amdgcn_mfma_f32_16x16x32_bf16(
            af[mi], bfr[ni], acc[mi][ni], 0, 0, 0);
    __builtin_amdgcn_s_setprio(0);
    __builtin_amdgcn_s_barrier();
    slot = (slot == 2) ? 0 : slot + 1;
  }

  const int lg = lane >> 4;
#pragma unroll
  for (int ni = 0; ni < NR; ++ni) {
    const int n = n0 + wc * RN + ni * 16 + lr;
    const float bb = bias[e * N + n];
#pragma unroll
    for (int mi = 0; mi < MR; ++mi) {
#pragma unroll
      for (int r = 0; r < 4; ++r) {
        const int ml = wr * RM + mi * 16 + lg * 4 + r;
        float v = acc[mi][ni][r] + bb;
        if (EPI == 1) {
          float z = 1.5957691216f * v + 0.07135481283f * v * v * v;
          float gl = v / (1.0f + __expf(-z));
          ((unsigned short*)Cout)[(size_t)(e * CAP + m0 + ml) * N + n] = f2bf(gl);
        } else {
          const int token = tokl[ml];
          v += xres[(size_t)token * DM + n];
          ((float*)Cout)[(size_t)token * (size_t)N + n] = v;
        }
      }
    }
  }
}

// ---------------- launch ----------------------------------------------------
extern "C" void kernel_launch(void* const* d_in, const int* in_sizes, int n_in,
                              void* d_out, int out_size, void* d_ws, size_t ws_size,
                              hipStream_t stream) {
  const float* x    = (const float*)d_in[0];
  const float* cent = (const float*)d_in[1];
  const float* ln_g = (const float*)d_in[2];
  const float* ln_b = (const float*)d_in[3];
  const float* w1   = (const float*)d_in[4];
  const float* b1   = (const float*)d_in[5];
  const float* w2   = (const float*)d_in[6];
  const float* b2   = (const float*)d_in[7];
  float* out = (float*)d_out;

  char* ws = (char*)d_ws;
  size_t off = 0;
  unsigned short* w1T = (unsigned short*)(ws + off); off += (size_t)NE * FF * DM * 2;
  unsigned short* w2T = (unsigned short*)(ws + off); off += (size_t)NE * DM * FF * 2;
  unsigned short* nrm = (unsigned short*)(ws + off); off += (size_t)T_TOK * DM * 2;
  unsigned short* h1  = (unsigned short*)(ws + off); off += (size_t)T_TOK * FF * 2;
  float* scores       = (float*)(ws + off);          off += (size_t)NE * T_TOK * 4;
  int* tok            = (int*)(ws + off);            off += (size_t)T_TOK * 4;

  ln_scores_k<<<dim3(T_TOK), 256, 0, stream>>>(x, ln_g, ln_b, cent, nrm, scores);
  fat_assign_transpose<<<dim3(1 + 4096), 1024, 0, stream>>>(
      scores, tok, w1, w2, w1T, w2T);
  gemm_ring<1, true, DM, FF, 256, 128, 512, 4, 2>
      <<<dim3(FF / 128, CAP / 256, NE), 512, 0, stream>>>(nrm, w1T, b1, tok, nullptr, h1);
  gemm_ring<2, false, FF, DM, 128, 128, 256, 2, 2>
      <<<dim3(DM / 128, CAP / 128, NE), 256, 0, stream>>>(h1, w2T, b2, tok, x, out);
}